// Round 9
// baseline (1096.723 us; speedup 1.0000x reference)
//
#include <hip/hip_runtime.h>

// Scaling-and-squaring integration of velocity fields.
// vel: [2, 160, 192, 160, 3] f32.  v0 = vel / 2^7;  7x: v = v + warp(v, v).
// Each step: dst[p] = src[p] + trilerp(src, p + src[p]) (coords clamped).
// Step 1 fuses the 2^-7 scale (power of two => bit-exact commute through lerp).
//
// R7 change: 4-channel PADDED intermediates (float4, 16B/voxel) in ws.
// R5 evidence: z-pair "vector" loads on the packed 12B-stride layout compiled
// back to dwords (time/FETCH/VALU identical to R2's 30-dword version) because
// corner windows are only 4B-aligned -- alignment is a layout property.
// Padded layout makes every gather a guaranteed global_load_dwordx4:
// 10 VMEM instrs/voxel (self x4 + 4 rows * 2 x4 + store x4) vs 30.
// Schedule: conv vel->A (stream), 6x padded->padded A<->B, final padded->out.
// Needs ws >= 2 * 157,286,400 B; falls back to the R5 packed path otherwise.

#define DD 160
#define HH 192
#define WW 160
#define VOX (DD * HH * WW)      // 4,915,200 voxels per batch
#define NB 2
#define FIELD (VOX * 3)         // packed floats per batch
#define PADBYTES ((size_t)NB * VOX * 16)   // one padded field: 157,286,400 B

struct __attribute__((packed, aligned(4))) pf4 { float x, y, z, w; };
struct __attribute__((packed, aligned(4))) pf2 { float x, y; };

// ---------- conversion: packed vel -> padded field ----------
__launch_bounds__(256)
__global__ void conv_kernel(const float* __restrict__ src,
                            float4* __restrict__ dst) {
    int idx = blockIdx.x * 256 + threadIdx.x;
    if (idx >= NB * VOX) return;
    const float* p = src + (size_t)idx * 3;
    float4 v;
    v.x = p[0]; v.y = p[1]; v.z = p[2]; v.w = 0.0f;
    dst[idx] = v;
}

// ---------- padded-input step; output padded or packed ----------
template <bool OUT_PACKED>
__launch_bounds__(256)
__global__ void step_pad(const float4* __restrict__ src,
                         float* __restrict__ dst, float s) {
    int idx = blockIdx.x * 256 + threadIdx.x;
    if (idx >= NB * VOX) return;
    int b  = idx / VOX;
    int r  = idx - b * VOX;
    int d  = r / (HH * WW);
    int r2 = r - d * (HH * WW);
    int h  = r2 / WW;
    int w  = r2 - h * WW;

    const float4* __restrict__ v = src + (size_t)b * VOX;

    // self velocity: one dwordx4
    float4 sv = v[r];

    float x = fminf(fmaxf((float)d + s * sv.x, 0.0f), (float)(DD - 1));
    float y = fminf(fmaxf((float)h + s * sv.y, 0.0f), (float)(HH - 1));
    float z = fminf(fmaxf((float)w + s * sv.z, 0.0f), (float)(WW - 1));

    float xf = floorf(x), yf = floorf(y), zf = floorf(z);
    int x0 = (int)xf, y0 = (int)yf, z0 = (int)zf;
    int x1 = min(x0 + 1, DD - 1);
    int y1 = min(y0 + 1, HH - 1);
    float wx = x - xf, wy = y - yf, wz = z - zf;
    float iwx = 1.0f - wx, iwy = 1.0f - wy, iwz = 1.0f - wz;

    // z window: slots zb, zb+1 (zb <= W-2 so zb+1 stays in-row)
    int zb = min(z0, WW - 2);
    bool sel = (z0 > zb);        // true iff z0 == W-1 (then wz == 0 exactly)

    int ro00 = (x0 * HH + y0) * WW + zb;
    int ro01 = (x0 * HH + y1) * WW + zb;
    int ro10 = (x1 * HH + y0) * WW + zb;
    int ro11 = (x1 * HH + y1) * WW + zb;

    // 4 corner rows x 2 slots: 8 guaranteed dwordx4 loads
    float4 p00a = v[ro00], p00b = v[ro00 + 1];
    float4 p01a = v[ro01], p01b = v[ro01 + 1];
    float4 p10a = v[ro10], p10b = v[ro10 + 1];
    float4 p11a = v[ro11], p11b = v[ro11 + 1];

    // cz0 = sel ? slot1 : slot0; cz1 = slot1 (wz==0 when sel => exact)
    float g000 = sel ? p00b.x : p00a.x, g001 = sel ? p00b.y : p00a.y, g002 = sel ? p00b.z : p00a.z;
    float g010 = sel ? p01b.x : p01a.x, g011 = sel ? p01b.y : p01a.y, g012 = sel ? p01b.z : p01a.z;
    float g100 = sel ? p10b.x : p10a.x, g101 = sel ? p10b.y : p10a.y, g102 = sel ? p10b.z : p10a.z;
    float g110 = sel ? p11b.x : p11a.x, g111 = sel ? p11b.y : p11a.y, g112 = sel ? p11b.z : p11a.z;

    float out0, out1, out2;
    {   // channel 0
        float c00 = g000 * iwz + p00b.x * wz;
        float c01 = g010 * iwz + p01b.x * wz;
        float c10 = g100 * iwz + p10b.x * wz;
        float c11 = g110 * iwz + p11b.x * wz;
        float c0 = c00 * iwy + c01 * wy;
        float c1 = c10 * iwy + c11 * wy;
        out0 = s * (sv.x + (c0 * iwx + c1 * wx));
    }
    {   // channel 1
        float c00 = g001 * iwz + p00b.y * wz;
        float c01 = g011 * iwz + p01b.y * wz;
        float c10 = g101 * iwz + p10b.y * wz;
        float c11 = g111 * iwz + p11b.y * wz;
        float c0 = c00 * iwy + c01 * wy;
        float c1 = c10 * iwy + c11 * wy;
        out1 = s * (sv.y + (c0 * iwx + c1 * wx));
    }
    {   // channel 2
        float c00 = g002 * iwz + p00b.z * wz;
        float c01 = g012 * iwz + p01b.z * wz;
        float c10 = g102 * iwz + p10b.z * wz;
        float c11 = g112 * iwz + p11b.z * wz;
        float c0 = c00 * iwy + c01 * wy;
        float c1 = c10 * iwy + c11 * wy;
        out2 = s * (sv.z + (c0 * iwx + c1 * wx));
    }

    if (OUT_PACKED) {
        float* o = dst + (size_t)b * FIELD + (size_t)r * 3;
        pf2 st; st.x = out0; st.y = out1;
        *(pf2*)o = st;
        o[2] = out2;
    } else {
        float4* o = (float4*)dst + (size_t)b * VOX + r;
        float4 t; t.x = out0; t.y = out1; t.z = out2; t.w = 0.0f;
        *o = t;
    }
}

// ---------- fallback: R5 packed step (known-good 126us) ----------
__launch_bounds__(256)
__global__ void step_kernel(const float* __restrict__ src,
                            float* __restrict__ dst, float s) {
    int idx = blockIdx.x * 256 + threadIdx.x;
    if (idx >= NB * VOX) return;
    int b  = idx / VOX;
    int r  = idx - b * VOX;
    int d  = r / (HH * WW);
    int r2 = r - d * (HH * WW);
    int h  = r2 / WW;
    int w  = r2 - h * WW;

    const float* __restrict__ v = src + (size_t)b * FIELD;
    float* __restrict__ o       = dst + (size_t)b * FIELD;

    pf2 sl = *(const pf2*)(v + r * 3);
    float rv0 = sl.x, rv1 = sl.y;
    float rv2 = v[r * 3 + 2];

    float x = fminf(fmaxf((float)d + s * rv0, 0.0f), (float)(DD - 1));
    float y = fminf(fmaxf((float)h + s * rv1, 0.0f), (float)(HH - 1));
    float z = fminf(fmaxf((float)w + s * rv2, 0.0f), (float)(WW - 1));

    float xf = floorf(x), yf = floorf(y), zf = floorf(z);
    int x0 = (int)xf, y0 = (int)yf, z0 = (int)zf;
    int x1 = min(x0 + 1, DD - 1);
    int y1 = min(y0 + 1, HH - 1);
    float wx = x - xf, wy = y - yf, wz = z - zf;
    float iwx = 1.0f - wx, iwy = 1.0f - wy, iwz = 1.0f - wz;

    int zb = min(z0, WW - 2);
    bool sel = (z0 > zb);

    int ro00 = ((x0 * HH + y0) * WW + zb) * 3;
    int ro01 = ((x0 * HH + y1) * WW + zb) * 3;
    int ro10 = ((x1 * HH + y0) * WW + zb) * 3;
    int ro11 = ((x1 * HH + y1) * WW + zb) * 3;

    pf4 a00 = *(const pf4*)(v + ro00); pf2 b00 = *(const pf2*)(v + ro00 + 4);
    pf4 a01 = *(const pf4*)(v + ro01); pf2 b01 = *(const pf2*)(v + ro01 + 4);
    pf4 a10 = *(const pf4*)(v + ro10); pf2 b10 = *(const pf2*)(v + ro10 + 4);
    pf4 a11 = *(const pf4*)(v + ro11); pf2 b11 = *(const pf2*)(v + ro11 + 4);

    float g000 = sel ? a00.w : a00.x, g001 = sel ? b00.x : a00.y, g002 = sel ? b00.y : a00.z;
    float g010 = sel ? a01.w : a01.x, g011 = sel ? b01.x : a01.y, g012 = sel ? b01.y : a01.z;
    float g100 = sel ? a10.w : a10.x, g101 = sel ? b10.x : a10.y, g102 = sel ? b10.y : a10.z;
    float g110 = sel ? a11.w : a11.x, g111 = sel ? b11.x : a11.y, g112 = sel ? b11.y : a11.z;

    float out0, out1, out2;
    {
        float c00 = g000 * iwz + a00.w * wz;
        float c01 = g010 * iwz + a01.w * wz;
        float c10 = g100 * iwz + a10.w * wz;
        float c11 = g110 * iwz + a11.w * wz;
        float c0 = c00 * iwy + c01 * wy;
        float c1 = c10 * iwy + c11 * wy;
        out0 = s * (rv0 + (c0 * iwx + c1 * wx));
    }
    {
        float c00 = g001 * iwz + b00.x * wz;
        float c01 = g011 * iwz + b01.x * wz;
        float c10 = g101 * iwz + b10.x * wz;
        float c11 = g111 * iwz + b11.x * wz;
        float c0 = c00 * iwy + c01 * wy;
        float c1 = c10 * iwy + c11 * wy;
        out1 = s * (rv1 + (c0 * iwx + c1 * wx));
    }
    {
        float c00 = g002 * iwz + b00.y * wz;
        float c01 = g012 * iwz + b01.y * wz;
        float c10 = g102 * iwz + b10.y * wz;
        float c11 = g112 * iwz + b11.y * wz;
        float c0 = c00 * iwy + c01 * wy;
        float c1 = c10 * iwy + c11 * wy;
        out2 = s * (rv2 + (c0 * iwx + c1 * wx));
    }

    pf2 st; st.x = out0; st.y = out1;
    *(pf2*)(o + r * 3) = st;
    o[r * 3 + 2] = out2;
}

extern "C" void kernel_launch(void* const* d_in, const int* in_sizes, int n_in,
                              void* d_out, int out_size, void* d_ws, size_t ws_size,
                              hipStream_t stream) {
    const float* vel = (const float*)d_in[0];
    float* out = (float*)d_out;

    const int nthreads = NB * VOX;                 // 9,830,400
    const int blocks = (nthreads + 255) / 256;     // 38,400 exact

    if (ws_size >= 2 * PADBYTES) {
        // padded path: conv -> 7 squaring steps (A<->B), final lands packed in d_out
        float4* A = (float4*)d_ws;
        float4* B = A + (size_t)NB * VOX;
        conv_kernel<<<blocks, 256, 0, stream>>>(vel, A);
        step_pad<false><<<blocks, 256, 0, stream>>>(A, (float*)B, 1.0f / 128.0f);
        step_pad<false><<<blocks, 256, 0, stream>>>(B, (float*)A, 1.0f);
        step_pad<false><<<blocks, 256, 0, stream>>>(A, (float*)B, 1.0f);
        step_pad<false><<<blocks, 256, 0, stream>>>(B, (float*)A, 1.0f);
        step_pad<false><<<blocks, 256, 0, stream>>>(A, (float*)B, 1.0f);
        step_pad<false><<<blocks, 256, 0, stream>>>(B, (float*)A, 1.0f);
        step_pad<true ><<<blocks, 256, 0, stream>>>(A, out, 1.0f);
    } else {
        // fallback: packed ping-pong (R5 path), ws >= 117,964,800 B
        float* ws = (float*)d_ws;
        step_kernel<<<blocks, 256, 0, stream>>>(vel, out, 1.0f / 128.0f);
        step_kernel<<<blocks, 256, 0, stream>>>(out, ws, 1.0f);
        step_kernel<<<blocks, 256, 0, stream>>>(ws, out, 1.0f);
        step_kernel<<<blocks, 256, 0, stream>>>(out, ws, 1.0f);
        step_kernel<<<blocks, 256, 0, stream>>>(ws, out, 1.0f);
        step_kernel<<<blocks, 256, 0, stream>>>(out, ws, 1.0f);
        step_kernel<<<blocks, 256, 0, stream>>>(ws, out, 1.0f);
    }
}

// Round 12
// 972.343 us; speedup vs baseline: 1.1279x; 1.1279x over previous
//
#include <hip/hip_runtime.h>

// Scaling-and-squaring integration: v0 = vel/128; 7x: v = v + warp(v,v).
// vel: [2, 160, 192, 160, 3] f32 packed.
//
// R9 evidence: time == hbm_bytes / ~2.2 TB/s across R2/R4/R7 regardless of
// VMEM instr count (padded dwordx4 gathers did NOT beat packed dwords), and
// FETCH == full field every step (L3 does not retain ping-pong writes).
// => bytes-limited. Only lever: fewer passes over HBM.
//
// R10 change: fuse adjacent steps. Stage-1 (step k) is recomputed per-block
// on tile+halo and staged in LDS; stage-2 (step k+1) gathers from LDS.
// Bit-exact: identical formulas, identical rounding, recomputation identical.
// Halo from displacement bound max|v_k| <= (6/128)*2^(k-1):
//   pair(1,2): disp<=0.094 -> halo 2;  pair(3,4): disp<=0.375 -> halo 2;
//   pair(5,6): disp<=1.5   -> halo 3;  step 7 plain (measured 126us kernel).
// Passes: 7 -> 4. LDS <= 62KB/block (64KB static limit), 512-thr blocks.
// Schedule: vel->ws (f12), ws->out (f34), out->ws (f56), ws->out (step7).

#define DD 160
#define HH 192
#define WW 160
#define VOX (DD * HH * WW)
#define NB 2
#define FIELD (VOX * 3)

struct __attribute__((packed, aligned(4))) pf4 { float x, y, z, w; };
struct __attribute__((packed, aligned(4))) pf2 { float x, y; };

__device__ __forceinline__ void ld3(const float* __restrict__ p,
                                    float& a, float& b, float& c) {
    a = p[0]; b = p[1]; c = p[2];
}

// one plain step at voxel (d,h,w): out = s*(src + trilerp(src, p + s*src))
__device__ __forceinline__ void step_point(const float* __restrict__ v,
                                           int d, int h, int w, float s,
                                           float& o0, float& o1, float& o2) {
    int base = ((d * HH + h) * WW + w) * 3;
    float rv0 = v[base], rv1 = v[base + 1], rv2 = v[base + 2];
    float x = fminf(fmaxf((float)d + s * rv0, 0.f), (float)(DD - 1));
    float y = fminf(fmaxf((float)h + s * rv1, 0.f), (float)(HH - 1));
    float z = fminf(fmaxf((float)w + s * rv2, 0.f), (float)(WW - 1));
    float xf = floorf(x), yf = floorf(y), zf = floorf(z);
    int x0 = (int)xf, y0 = (int)yf, z0 = (int)zf;
    int x1 = min(x0 + 1, DD - 1), y1 = min(y0 + 1, HH - 1), z1 = min(z0 + 1, WW - 1);
    float wx = x - xf, wy = y - yf, wz = z - zf;
    float iwx = 1.f - wx, iwy = 1.f - wy, iwz = 1.f - wz;
    int ro00 = ((x0 * HH + y0) * WW) * 3, ro01 = ((x0 * HH + y1) * WW) * 3;
    int ro10 = ((x1 * HH + y0) * WW) * 3, ro11 = ((x1 * HH + y1) * WW) * 3;
    int zo0 = z0 * 3, zo1 = z1 * 3;
    float a000,b000,c000,a001,b001,c001,a010,b010,c010,a011,b011,c011;
    float a100,b100,c100,a101,b101,c101,a110,b110,c110,a111,b111,c111;
    ld3(v + ro00 + zo0, a000, b000, c000); ld3(v + ro00 + zo1, a001, b001, c001);
    ld3(v + ro01 + zo0, a010, b010, c010); ld3(v + ro01 + zo1, a011, b011, c011);
    ld3(v + ro10 + zo0, a100, b100, c100); ld3(v + ro10 + zo1, a101, b101, c101);
    ld3(v + ro11 + zo0, a110, b110, c110); ld3(v + ro11 + zo1, a111, b111, c111);
    {
        float c00 = a000 * iwz + a001 * wz, c01 = a010 * iwz + a011 * wz;
        float c10 = a100 * iwz + a101 * wz, c11 = a110 * iwz + a111 * wz;
        float c0 = c00 * iwy + c01 * wy, c1 = c10 * iwy + c11 * wy;
        o0 = s * (rv0 + (c0 * iwx + c1 * wx));
    }
    {
        float c00 = b000 * iwz + b001 * wz, c01 = b010 * iwz + b011 * wz;
        float c10 = b100 * iwz + b101 * wz, c11 = b110 * iwz + b111 * wz;
        float c0 = c00 * iwy + c01 * wy, c1 = c10 * iwy + c11 * wy;
        o1 = s * (rv1 + (c0 * iwx + c1 * wx));
    }
    {
        float c00 = c000 * iwz + c001 * wz, c01 = c010 * iwz + c011 * wz;
        float c10 = c100 * iwz + c101 * wz, c11 = c110 * iwz + c111 * wz;
        float c0 = c00 * iwy + c01 * wy, c1 = c10 * iwy + c11 * wy;
        o2 = s * (rv2 + (c0 * iwx + c1 * wx));
    }
}

// fused pair: stage-1 (scale s1) on tile+halo -> LDS; stage-2 (s=1) from LDS.
template <int HALO, int TD, int TH, int TW, int BT>
__launch_bounds__(BT)
__global__ void fused_pair(const float* __restrict__ src,
                           float* __restrict__ dst, float s1) {
    constexpr int SD = TD + 2 * HALO, SH = TH + 2 * HALO, SW = TW + 2 * HALO;
    constexpr int SN = SD * SH * SW;
    __shared__ float sx[SN], sy[SN], sz[SN];
    constexpr int tilesD = DD / TD, tilesH = HH / TH, tilesW = WW / TW;
    constexpr int nwg1 = tilesD * tilesH * tilesW * NB;   // divisible by 8

    // XCD-chunked swizzle: consecutive logical tiles land on the same XCD.
    int bid = (blockIdx.x & 7) * (nwg1 >> 3) + (blockIdx.x >> 3);
    int b  = bid / (tilesD * tilesH * tilesW);
    int t  = bid - b * (tilesD * tilesH * tilesW);
    int td = t / (tilesH * tilesW);
    int t2 = t - td * (tilesH * tilesW);
    int th = t2 / tilesW;
    int tw = t2 - th * tilesW;
    int od = td * TD - HALO, oh = th * TH - HALO, ow = tw * TW - HALO;

    const float* __restrict__ v = src + (size_t)b * FIELD;
    float* __restrict__ o       = dst + (size_t)b * FIELD;

    // ---- stage 1: step k on staged region (coords clamped; extras unused)
    for (int i = threadIdx.x; i < SN; i += BT) {
        int ld = i / (SH * SW);
        int i2 = i - ld * (SH * SW);
        int lh = i2 / SW;
        int lw = i2 - lh * SW;
        int qd = min(max(od + ld, 0), DD - 1);
        int qh = min(max(oh + lh, 0), HH - 1);
        int qw = min(max(ow + lw, 0), WW - 1);
        float r0, r1, r2;
        step_point(v, qd, qh, qw, s1, r0, r1, r2);
        sx[i] = r0; sy[i] = r1; sz[i] = r2;
    }
    __syncthreads();

    // ---- stage 2: step k+1 on inner tile, gathers from LDS
    for (int j = threadIdx.x; j < TD * TH * TW; j += BT) {
        int pd = j / (TH * TW);
        int j2 = j - pd * (TH * TW);
        int ph = j2 / TW;
        int pw = j2 - ph * TW;
        int gd = td * TD + pd, gh = th * TH + ph, gw = tw * TW + pw;
        int li = ((pd + HALO) * SH + (ph + HALO)) * SW + (pw + HALO);
        float rv0 = sx[li], rv1 = sy[li], rv2 = sz[li];
        float x = fminf(fmaxf((float)gd + rv0, 0.f), (float)(DD - 1));
        float y = fminf(fmaxf((float)gh + rv1, 0.f), (float)(HH - 1));
        float z = fminf(fmaxf((float)gw + rv2, 0.f), (float)(WW - 1));
        float xf = floorf(x), yf = floorf(y), zf = floorf(z);
        int x0 = (int)xf, y0 = (int)yf, z0 = (int)zf;
        int x1 = min(x0 + 1, DD - 1), y1 = min(y0 + 1, HH - 1), z1 = min(z0 + 1, WW - 1);
        float wx = x - xf, wy = y - yf, wz = z - zf;
        float iwx = 1.f - wx, iwy = 1.f - wy, iwz = 1.f - wz;
        // LDS-local corners; analytically in-range (halo bound), clamp = safety
        int ix0 = min(max(x0 - od, 0), SD - 1), ix1 = min(max(x1 - od, 0), SD - 1);
        int iy0 = min(max(y0 - oh, 0), SH - 1), iy1 = min(max(y1 - oh, 0), SH - 1);
        int iz0 = min(max(z0 - ow, 0), SW - 1), iz1 = min(max(z1 - ow, 0), SW - 1);
        int i000 = (ix0 * SH + iy0) * SW + iz0, i001 = (ix0 * SH + iy0) * SW + iz1;
        int i010 = (ix0 * SH + iy1) * SW + iz0, i011 = (ix0 * SH + iy1) * SW + iz1;
        int i100 = (ix1 * SH + iy0) * SW + iz0, i101 = (ix1 * SH + iy0) * SW + iz1;
        int i110 = (ix1 * SH + iy1) * SW + iz0, i111 = (ix1 * SH + iy1) * SW + iz1;
        float o0, o1, o2;
        {
            float c00 = sx[i000] * iwz + sx[i001] * wz, c01 = sx[i010] * iwz + sx[i011] * wz;
            float c10 = sx[i100] * iwz + sx[i101] * wz, c11 = sx[i110] * iwz + sx[i111] * wz;
            float c0 = c00 * iwy + c01 * wy, c1 = c10 * iwy + c11 * wy;
            o0 = rv0 + (c0 * iwx + c1 * wx);
        }
        {
            float c00 = sy[i000] * iwz + sy[i001] * wz, c01 = sy[i010] * iwz + sy[i011] * wz;
            float c10 = sy[i100] * iwz + sy[i101] * wz, c11 = sy[i110] * iwz + sy[i111] * wz;
            float c0 = c00 * iwy + c01 * wy, c1 = c10 * iwy + c11 * wy;
            o1 = rv1 + (c0 * iwx + c1 * wx);
        }
        {
            float c00 = sz[i000] * iwz + sz[i001] * wz, c01 = sz[i010] * iwz + sz[i011] * wz;
            float c10 = sz[i100] * iwz + sz[i101] * wz, c11 = sz[i110] * iwz + sz[i111] * wz;
            float c0 = c00 * iwy + c01 * wy, c1 = c10 * iwy + c11 * wy;
            o2 = rv2 + (c0 * iwx + c1 * wx);
        }
        float* op = o + (size_t)((gd * HH + gh) * WW + gw) * 3;
        pf2 st; st.x = o0; st.y = o1;
        *(pf2*)op = st;
        op[2] = o2;
    }
}

// plain packed step (R5 path, measured 126us) for the final step
__launch_bounds__(256)
__global__ void step_kernel(const float* __restrict__ src,
                            float* __restrict__ dst, float s) {
    int idx = blockIdx.x * 256 + threadIdx.x;
    if (idx >= NB * VOX) return;
    int b  = idx / VOX;
    int r  = idx - b * VOX;
    int d  = r / (HH * WW);
    int r2 = r - d * (HH * WW);
    int h  = r2 / WW;
    int w  = r2 - h * WW;
    const float* __restrict__ v = src + (size_t)b * FIELD;
    float* __restrict__ o       = dst + (size_t)b * FIELD;
    float o0, o1, o2;
    step_point(v, d, h, w, s, o0, o1, o2);
    float* op = o + (size_t)r * 3;
    pf2 st; st.x = o0; st.y = o1;
    *(pf2*)op = st;
    op[2] = o2;
}

extern "C" void kernel_launch(void* const* d_in, const int* in_sizes, int n_in,
                              void* d_out, int out_size, void* d_ws, size_t ws_size,
                              hipStream_t stream) {
    const float* vel = (const float*)d_in[0];
    float* out = (float*)d_out;
    float* ws  = (float*)d_ws;   // >= one packed field (117,964,800 B)

    // fused pair (1,2): halo 2, tile 8x8x32 -> 20*24*5*2 = 4800 blocks
    fused_pair<2, 8, 8, 32, 512><<<4800, 512, 0, stream>>>(vel, ws, 1.0f / 128.0f);
    // fused pair (3,4): halo 2
    fused_pair<2, 8, 8, 32, 512><<<4800, 512, 0, stream>>>(ws, out, 1.0f);
    // fused pair (5,6): halo 3, tile 8x8x20 -> 20*24*8*2 = 7680 blocks
    fused_pair<3, 8, 8, 20, 512><<<7680, 512, 0, stream>>>(out, ws, 1.0f);
    // step 7: plain packed
    step_kernel<<<(NB * VOX + 255) / 256, 256, 0, stream>>>(ws, out, 1.0f);
}